// Round 2
// baseline (584.343 us; speedup 1.0000x reference)
//
#include <hip/hip_runtime.h>

#define HW 16384
#define C_IN 256
#define C_MID 128
#define C_OUT 32
#define EPSF 1e-5f

// ---------------- Kernel 1: per-(b,c) stats ----------------
__global__ __launch_bounds__(256) void k_stats(const float* __restrict__ content,
                                               const float* __restrict__ style,
                                               float* __restrict__ cmean,
                                               float* __restrict__ crstd,
                                               float* __restrict__ smean) {
    int bc = blockIdx.x;            // 0 .. B*C-1 = 2047
    const float4* cp = (const float4*)(content + (size_t)bc * HW);
    const float4* sp = (const float4*)(style + (size_t)bc * HW);
    int t = threadIdx.x;
    float cs = 0.f, cq = 0.f, ss = 0.f;
    #pragma unroll
    for (int i = 0; i < 16; ++i) {
        float4 v = cp[t + 256 * i];
        cs += v.x + v.y + v.z + v.w;
        cq += v.x * v.x + v.y * v.y + v.z * v.z + v.w * v.w;
        float4 u = sp[t + 256 * i];
        ss += u.x + u.y + u.z + u.w;
    }
    __shared__ float r0[256], r1[256], r2[256];
    r0[t] = cs; r1[t] = cq; r2[t] = ss;
    __syncthreads();
    for (int off = 128; off > 0; off >>= 1) {
        if (t < off) { r0[t] += r0[t + off]; r1[t] += r1[t + off]; r2[t] += r2[t + off]; }
        __syncthreads();
    }
    if (t == 0) {
        float n = (float)HW;
        float m = r0[0] / n;
        float var = (r1[0] - r0[0] * r0[0] / n) / (n - 1.f);
        cmean[bc] = m;
        crstd[bc] = 1.f / sqrtf(var + EPSF);
        smean[bc] = r2[0] / n;
    }
}

// ---------------- Kernel 2: fused net = conv1x1(relu(conv1x1(x_nor))) ----
// block tile: 128 o x 64 p ; 256 threads = (ty 0..31) x (tx 0..7); micro 4x8
__global__ __launch_bounds__(256) void k_net(const float* __restrict__ x,
                                             const float* __restrict__ w1,
                                             const float* __restrict__ b1,
                                             const float* __restrict__ w2,
                                             const float* __restrict__ b2,
                                             const float* __restrict__ mean,
                                             const float* __restrict__ rstd,
                                             float* __restrict__ outF,
                                             int use_rstd) {
    __shared__ float sW[32 * 132];   // conv1: [k][o] stride 132 ; conv2: [k][o2] stride 33
    __shared__ float sX[32 * 64];    // [k][p]
    __shared__ float sT[128 * 64];   // [o][p]
    int t = threadIdx.x;
    int tx = t & 7, ty = t >> 3;
    int p0 = blockIdx.x * 64;
    int b = blockIdx.y;
    const float* xb = x + (size_t)b * C_IN * HW;

    float acc[4][8];
    #pragma unroll
    for (int i = 0; i < 4; ++i)
        #pragma unroll
        for (int j = 0; j < 8; ++j) acc[i][j] = 0.f;

    for (int kc = 0; kc < 8; ++kc) {
        __syncthreads();
        {   // W1 chunk: 128 o x 32 c -> sW[c][o]
            int cl = t & 31, ob = t >> 5;
            #pragma unroll
            for (int pass = 0; pass < 16; ++pass) {
                int o = pass * 8 + ob;
                sW[cl * 132 + o] = w1[o * 256 + kc * 32 + cl];
            }
        }
        {   // X chunk: 32 c x 64 p, normalized on load
            int p = t & 63, kl = t >> 6;
            #pragma unroll
            for (int pass = 0; pass < 8; ++pass) {
                int k = pass * 4 + kl;
                int c = kc * 32 + k;
                float v = xb[(size_t)c * HW + p0 + p];
                float m = mean[b * 256 + c];
                v = use_rstd ? (v - m) * rstd[b * 256 + c] : (v - m);
                sX[k * 64 + p] = v;
            }
        }
        __syncthreads();
        #pragma unroll
        for (int k = 0; k < 32; ++k) {
            float4 a4 = *(const float4*)&sW[k * 132 + ty * 4];
            float4 b4a = *(const float4*)&sX[k * 64 + tx * 8];
            float4 b4b = *(const float4*)&sX[k * 64 + tx * 8 + 4];
            float a[4] = {a4.x, a4.y, a4.z, a4.w};
            float bb[8] = {b4a.x, b4a.y, b4a.z, b4a.w, b4b.x, b4b.y, b4b.z, b4b.w};
            #pragma unroll
            for (int i = 0; i < 4; ++i)
                #pragma unroll
                for (int j = 0; j < 8; ++j)
                    acc[i][j] = fmaf(a[i], bb[j], acc[i][j]);
        }
    }
    __syncthreads();
    #pragma unroll
    for (int i = 0; i < 4; ++i) {
        int o = ty * 4 + i;
        float bias = b1[o];
        #pragma unroll
        for (int j = 0; j < 8; ++j)
            sT[o * 64 + tx * 8 + j] = fmaxf(acc[i][j] + bias, 0.f);
    }
    {
        int kl = t & 127, ob = t >> 7;
        #pragma unroll
        for (int pass = 0; pass < 16; ++pass) {
            int o2 = pass * 2 + ob;
            sW[kl * 33 + o2] = w2[o2 * 128 + kl];
        }
    }
    __syncthreads();
    float acc2[8];
    #pragma unroll
    for (int j = 0; j < 8; ++j) acc2[j] = 0.f;
    #pragma unroll 8
    for (int k = 0; k < 128; ++k) {
        float a = sW[k * 33 + ty];
        float4 b4a = *(const float4*)&sT[k * 64 + tx * 8];
        float4 b4b = *(const float4*)&sT[k * 64 + tx * 8 + 4];
        float bb[8] = {b4a.x, b4a.y, b4a.z, b4a.w, b4b.x, b4b.y, b4b.z, b4b.w};
        #pragma unroll
        for (int j = 0; j < 8; ++j) acc2[j] = fmaf(a, bb[j], acc2[j]);
    }
    float bias2 = b2[ty];
    float4 o1 = make_float4(acc2[0] + bias2, acc2[1] + bias2, acc2[2] + bias2, acc2[3] + bias2);
    float4 o2v = make_float4(acc2[4] + bias2, acc2[5] + bias2, acc2[6] + bias2, acc2[7] + bias2);
    float* dst = outF + (size_t)b * C_OUT * HW + (size_t)ty * HW + p0 + tx * 8;
    *(float4*)dst = o1;
    *(float4*)(dst + 4) = o2v;
}

// ---------------- Kernel 3: partial gram of sF ----------
__global__ __launch_bounds__(256) void k_gram(const float* __restrict__ sF,
                                              float* __restrict__ partial) {
    __shared__ float sS[32 * 257];
    int b = blockIdx.y, sl = blockIdx.x;
    int t = threadIdx.x;
    const float* base = sF + (size_t)b * C_OUT * HW + sl * 1024;
    int i = t >> 3, jb = (t & 7) * 4;
    float acc[4] = {0.f, 0.f, 0.f, 0.f};
    for (int ch = 0; ch < 4; ++ch) {
        __syncthreads();
        #pragma unroll
        for (int r = 0; r < 32; ++r)
            sS[r * 257 + t] = base[(size_t)r * HW + ch * 256 + t];
        __syncthreads();
        for (int n = 0; n < 256; ++n) {
            float si = sS[i * 257 + n];
            #pragma unroll
            for (int q = 0; q < 4; ++q)
                acc[q] = fmaf(si, sS[(jb + q) * 257 + n], acc[q]);
        }
    }
    float* dst = partial + ((size_t)(b * 16 + sl)) * 1024 + t * 4;
    #pragma unroll
    for (int q = 0; q < 4; ++q) dst[q] = acc[q];
}

// ---------------- Kernel 4: reduce partials + softmax + scale ----------
__global__ __launch_bounds__(1024) void k_softmax(const float* __restrict__ partial,
                                                  float* __restrict__ scov) {
    int b = blockIdx.x;
    int j = threadIdx.x, i = threadIdx.y;
    float v = 0.f;
    #pragma unroll
    for (int s = 0; s < 16; ++s)
        v += partial[((size_t)(b * 16 + s)) * 1024 + i * 32 + j];
    v *= (1.f / (float)HW);
    float m = v;
    #pragma unroll
    for (int d = 16; d > 0; d >>= 1) m = fmaxf(m, __shfl_xor(m, d, 32));
    float e = expf(v - m);
    float sum = e;
    #pragma unroll
    for (int d = 16; d > 0; d >>= 1) sum += __shfl_xor(sum, d, 32);
    scov[(size_t)b * 1024 + i * 32 + j] = e / sum * 0.17677669529663687f;
}

// ---------------- Kernel 5: out = wu@(scov@cF) + bu + smean + content ----
__global__ __launch_bounds__(256) void k_final(const float* __restrict__ cF,
                                               const float* __restrict__ scov,
                                               const float* __restrict__ wu,
                                               const float* __restrict__ bu,
                                               const float* __restrict__ smean,
                                               const float* __restrict__ content,
                                               float* __restrict__ out) {
    __shared__ float sCov[1024];
    __shared__ float sC[32 * 64];
    __shared__ float sG[32 * 64];
    __shared__ float sWu[32 * 260];
    int t = threadIdx.x;
    int p0 = blockIdx.x * 64;
    int b = blockIdx.y;
    #pragma unroll
    for (int q = 0; q < 4; ++q) sCov[t + 256 * q] = scov[(size_t)b * 1024 + t + 256 * q];
    {
        int p = t & 63, rb = t >> 6;
        #pragma unroll
        for (int pass = 0; pass < 8; ++pass) {
            int r = pass * 4 + rb;
            sC[r * 64 + p] = cF[(size_t)b * C_OUT * HW + (size_t)r * HW + p0 + p];
        }
    }
    {
        int k = t & 31, ob = t >> 5;
        #pragma unroll
        for (int pass = 0; pass < 32; ++pass) {
            int o = pass * 8 + ob;
            sWu[k * 260 + o] = wu[o * 32 + k];
        }
    }
    __syncthreads();
    {
        int gp = t & 63, gib = (t >> 6) * 8;
        #pragma unroll
        for (int rr = 0; rr < 8; ++rr) {
            int gi = gib + rr;
            float a = 0.f;
            #pragma unroll
            for (int k = 0; k < 32; ++k)
                a = fmaf(sCov[gi * 32 + k], sC[k * 64 + gp], a);
            sG[gi * 64 + gp] = a;
        }
    }
    __syncthreads();
    int tx = t & 7, ty = t >> 3;
    float acc[8][8];
    #pragma unroll
    for (int i = 0; i < 8; ++i)
        #pragma unroll
        for (int j = 0; j < 8; ++j) acc[i][j] = 0.f;
    #pragma unroll 4
    for (int k = 0; k < 32; ++k) {
        float4 a4a = *(const float4*)&sWu[k * 260 + ty * 8];
        float4 a4b = *(const float4*)&sWu[k * 260 + ty * 8 + 4];
        float4 b4a = *(const float4*)&sG[k * 64 + tx * 8];
        float4 b4b = *(const float4*)&sG[k * 64 + tx * 8 + 4];
        float a[8] = {a4a.x, a4a.y, a4a.z, a4a.w, a4b.x, a4b.y, a4b.z, a4b.w};
        float bb[8] = {b4a.x, b4a.y, b4a.z, b4a.w, b4b.x, b4b.y, b4b.z, b4b.w};
        #pragma unroll
        for (int i = 0; i < 8; ++i)
            #pragma unroll
            for (int j = 0; j < 8; ++j)
                acc[i][j] = fmaf(a[i], bb[j], acc[i][j]);
    }
    #pragma unroll
    for (int i = 0; i < 8; ++i) {
        int o = ty * 8 + i;
        float add = bu[o] + smean[b * 256 + o];
        const float* csrc = content + (size_t)b * C_IN * HW + (size_t)o * HW + p0 + tx * 8;
        float* dst = out + (size_t)b * C_IN * HW + (size_t)o * HW + p0 + tx * 8;
        float4 c0 = *(const float4*)csrc;
        float4 c1 = *(const float4*)(csrc + 4);
        float4 r0 = make_float4(acc[i][0] + add + c0.x, acc[i][1] + add + c0.y,
                                acc[i][2] + add + c0.z, acc[i][3] + add + c0.w);
        float4 r1 = make_float4(acc[i][4] + add + c1.x, acc[i][5] + add + c1.y,
                                acc[i][6] + add + c1.z, acc[i][7] + add + c1.w);
        *(float4*)dst = r0;
        *(float4*)(dst + 4) = r1;
    }
}

extern "C" void kernel_launch(void* const* d_in, const int* in_sizes, int n_in,
                              void* d_out, int out_size, void* d_ws, size_t ws_size,
                              hipStream_t stream) {
    const float* content = (const float*)d_in[0];
    const float* style   = (const float*)d_in[1];
    const float* w1      = (const float*)d_in[2];
    const float* b1      = (const float*)d_in[3];
    const float* w2      = (const float*)d_in[4];
    const float* b2      = (const float*)d_in[5];
    const float* wu      = (const float*)d_in[6];
    const float* bu      = (const float*)d_in[7];
    float* out = (float*)d_out;
    float* ws  = (float*)d_ws;

    float* cmean   = ws;                 // 2048 used (4096 reserved)
    float* crstd   = ws + 4096;          // 2048 used
    float* smean   = ws + 8192;          // 2048 used
    float* scov    = ws + 12288;         // 8192
    float* partial = ws + 20480;         // 131072
    float* cF      = ws + 151552;        // 4194304 floats
    float* sF      = cF + 4194304;       // 4194304 floats

    k_stats<<<dim3(2048), 256, 0, stream>>>(content, style, cmean, crstd, smean);
    k_net<<<dim3(256, 8), 256, 0, stream>>>(content, w1, b1, w2, b2, cmean, crstd, cF, 1);
    k_net<<<dim3(256, 8), 256, 0, stream>>>(style, w1, b1, w2, b2, smean, crstd, sF, 0);
    k_gram<<<dim3(16, 8), 256, 0, stream>>>(sF, partial);
    k_softmax<<<dim3(8), dim3(32, 32), 0, stream>>>(partial, scov);
    k_final<<<dim3(256, 8), 256, 0, stream>>>(cF, scov, wu, bu, smean, content, out);
}

// Round 3
// 254.617 us; speedup vs baseline: 2.2950x; 2.2950x over previous
//
#include <hip/hip_runtime.h>

#define HW 16384
#define C_IN 256
#define C_MID 128
#define C_OUT 32
#define EPSF 1e-5f

typedef __bf16 bf16x8 __attribute__((ext_vector_type(8)));
typedef __bf16 bf16x4 __attribute__((ext_vector_type(4)));
typedef float f32x4 __attribute__((ext_vector_type(4)));

// ---------------- Kernel 1: per-(b,c) stats ----------------
__global__ __launch_bounds__(256) void k_stats(const float* __restrict__ content,
                                               const float* __restrict__ style,
                                               float* __restrict__ cmean,
                                               float* __restrict__ crstd,
                                               float* __restrict__ smean) {
    int bc = blockIdx.x;            // 0 .. 2047
    const float4* cp = (const float4*)(content + (size_t)bc * HW);
    const float4* sp = (const float4*)(style + (size_t)bc * HW);
    int t = threadIdx.x;
    float cs = 0.f, cq = 0.f, ss = 0.f;
    #pragma unroll
    for (int i = 0; i < 16; ++i) {
        float4 v = cp[t + 256 * i];
        cs += v.x + v.y + v.z + v.w;
        cq += v.x * v.x + v.y * v.y + v.z * v.z + v.w * v.w;
        float4 u = sp[t + 256 * i];
        ss += u.x + u.y + u.z + u.w;
    }
    __shared__ float r0[256], r1[256], r2[256];
    r0[t] = cs; r1[t] = cq; r2[t] = ss;
    __syncthreads();
    for (int off = 128; off > 0; off >>= 1) {
        if (t < off) { r0[t] += r0[t + off]; r1[t] += r1[t + off]; r2[t] += r2[t + off]; }
        __syncthreads();
    }
    if (t == 0) {
        float n = (float)HW;
        float m = r0[0] / n;
        float var = (r1[0] - r0[0] * r0[0] / n) / (n - 1.f);
        cmean[bc] = m;
        crstd[bc] = 1.f / sqrtf(var + EPSF);
        smean[bc] = r2[0] / n;
    }
}

// ---------------- Prep: fold norm into conv1 weights (bf16) ----------------
// W1c[b][o][c] = w1[o][c]*crstd[b][c]; bias1c[b][o] = b1[o] - sum_c w1*cmean*crstd
// W1s[o][c]    = w1[o][c]            ; bias1s[b][o] = b1[o] - sum_c w1*smean
__global__ __launch_bounds__(256) void k_wprep(const float* __restrict__ w1,
                                               const float* __restrict__ b1,
                                               const float* __restrict__ cmean,
                                               const float* __restrict__ crstd,
                                               const float* __restrict__ smean,
                                               __bf16* __restrict__ W1c,
                                               float* __restrict__ bias1c,
                                               __bf16* __restrict__ W1s,
                                               float* __restrict__ bias1s) {
    int o = blockIdx.x, b = blockIdx.y, t = threadIdx.x;
    float w = w1[o * 256 + t];
    float r = crstd[b * 256 + t];
    float wc = w * r;
    W1c[((size_t)(b * 128 + o)) * 256 + t] = (__bf16)wc;
    if (b == 0) W1s[o * 256 + t] = (__bf16)w;
    float pc = wc * cmean[b * 256 + t];
    float ps = w * smean[b * 256 + t];
    __shared__ float rA[256], rB[256];
    rA[t] = pc; rB[t] = ps;
    __syncthreads();
    for (int off = 128; off > 0; off >>= 1) {
        if (t < off) { rA[t] += rA[t + off]; rB[t] += rB[t + off]; }
        __syncthreads();
    }
    if (t == 0) {
        bias1c[b * 128 + o] = b1[o] - rA[0];
        bias1s[b * 128 + o] = b1[o] - rB[0];
    }
}

__global__ __launch_bounds__(256) void k_w2prep(const float* __restrict__ w2,
                                                __bf16* __restrict__ W2b) {
    int i = blockIdx.x * 256 + threadIdx.x;   // 4096 total
    if (i < 4096) W2b[i] = (__bf16)w2[i];
}

// ---------------- Kernel 2: MFMA fused net ----------------
// block: 256 thr (4 waves), tile 128o x 64p, K=256. X staged [p][c] bf16
// XOR-swizzled (byte ^= (p&7)<<4). conv1 per wave: o-slice wv*32, all p.
// conv2 per wave: p-slice wv*16, all o2=32. Weights (A-frags) from global/L2.
__global__ __launch_bounds__(256) void k_net_mfma(const float* __restrict__ x,
                                                  const __bf16* __restrict__ W1,
                                                  const float* __restrict__ bias1,
                                                  const __bf16* __restrict__ W2,
                                                  const float* __restrict__ b2,
                                                  float* __restrict__ outF,
                                                  int w1_per_batch) {
    __shared__ __bf16 Xl[64 * 256];   // 32 KB, [p][c] swizzled
    __shared__ __bf16 Tl[64 * 128];   // 16 KB, [p][o] swizzled
    const int tid = threadIdx.x;
    const int l = tid & 63, wv = tid >> 6;
    const int lr = l & 15, g = l >> 4;
    const int sw = (lr & 7) << 4;     // p&7 == lr&7 for all p used below
    const int p0 = blockIdx.x * 64;
    const int b = blockIdx.y;
    const float* xb = x + (size_t)b * C_IN * HW;

    // ---- stage X[c][p] (global f32) -> Xl[p][c] (bf16, swizzled)
    {
        const int p = wv * 16 + lr;
        const float* xp = xb + p0 + p;
        char* row = (char*)&Xl[p * 256];
        #pragma unroll 4
        for (int cc = 0; cc < 16; ++cc) {
            const int c = cc * 16 + g * 4;
            float f0 = xp[(size_t)(c + 0) * HW];
            float f1 = xp[(size_t)(c + 1) * HW];
            float f2 = xp[(size_t)(c + 2) * HW];
            float f3 = xp[(size_t)(c + 3) * HW];
            bf16x4 v;
            v[0] = (__bf16)f0; v[1] = (__bf16)f1; v[2] = (__bf16)f2; v[3] = (__bf16)f3;
            *(bf16x4*)(row + ((c * 2) ^ sw)) = v;
        }
    }
    __syncthreads();

    // ---- conv1: acc[mt][nt] over kt (K=256 in 8 steps of 32)
    const f32x4 zero4 = {0.f, 0.f, 0.f, 0.f};
    f32x4 acc[2][4];
    #pragma unroll
    for (int mt = 0; mt < 2; ++mt)
        #pragma unroll
        for (int nt = 0; nt < 4; ++nt) acc[mt][nt] = zero4;

    const __bf16* W1b = W1 + (w1_per_batch ? ((size_t)b << 15) : 0);
    const __bf16* wrow0 = W1b + (size_t)(wv * 32 + lr) * 256 + g * 8;
    const __bf16* wrow1 = wrow0 + 16 * 256;

    #pragma unroll
    for (int kt = 0; kt < 8; ++kt) {
        bf16x8 a0 = *(const bf16x8*)(wrow0 + kt * 32);
        bf16x8 a1 = *(const bf16x8*)(wrow1 + kt * 32);
        #pragma unroll
        for (int nt = 0; nt < 4; ++nt) {
            const char* xrow = (const char*)&Xl[(nt * 16 + lr) * 256];
            bf16x8 bfr = *(const bf16x8*)(xrow + (((kt * 32 + g * 8) * 2) ^ sw));
            acc[0][nt] = __builtin_amdgcn_mfma_f32_16x16x32_bf16(a0, bfr, acc[0][nt], 0, 0, 0);
            acc[1][nt] = __builtin_amdgcn_mfma_f32_16x16x32_bf16(a1, bfr, acc[1][nt], 0, 0, 0);
        }
    }

    // ---- bias + relu -> Tl[p][o] bf16 (swizzled)
    float4 bia[2];
    bia[0] = *(const float4*)&bias1[b * 128 + wv * 32 + g * 4];
    bia[1] = *(const float4*)&bias1[b * 128 + wv * 32 + 16 + g * 4];
    #pragma unroll
    for (int mt = 0; mt < 2; ++mt) {
        #pragma unroll
        for (int nt = 0; nt < 4; ++nt) {
            const int p = nt * 16 + lr;
            char* trow = (char*)&Tl[p * 128];
            const int ob = (wv * 32 + mt * 16 + g * 4) * 2;
            bf16x4 tv;
            tv[0] = (__bf16)fmaxf(acc[mt][nt][0] + bia[mt].x, 0.f);
            tv[1] = (__bf16)fmaxf(acc[mt][nt][1] + bia[mt].y, 0.f);
            tv[2] = (__bf16)fmaxf(acc[mt][nt][2] + bia[mt].z, 0.f);
            tv[3] = (__bf16)fmaxf(acc[mt][nt][3] + bia[mt].w, 0.f);
            *(bf16x4*)(trow + (ob ^ sw)) = tv;
        }
    }
    __syncthreads();

    // ---- conv2: o2=32, K=128; wave wv owns p-slice wv*16
    f32x4 acc2[2];
    acc2[0] = zero4; acc2[1] = zero4;
    const int p = wv * 16 + lr;
    const char* trow = (const char*)&Tl[p * 128];
    const __bf16* w2r0 = W2 + (size_t)lr * 128 + g * 8;
    const __bf16* w2r1 = w2r0 + 16 * 128;
    #pragma unroll
    for (int kt = 0; kt < 4; ++kt) {
        bf16x8 bfr = *(const bf16x8*)(trow + (((kt * 32 + g * 8) * 2) ^ sw));
        bf16x8 a0 = *(const bf16x8*)(w2r0 + kt * 32);
        bf16x8 a1 = *(const bf16x8*)(w2r1 + kt * 32);
        acc2[0] = __builtin_amdgcn_mfma_f32_16x16x32_bf16(a0, bfr, acc2[0], 0, 0, 0);
        acc2[1] = __builtin_amdgcn_mfma_f32_16x16x32_bf16(a1, bfr, acc2[1], 0, 0, 0);
    }
    float4 bb0 = *(const float4*)&b2[g * 4];
    float4 bb1 = *(const float4*)&b2[16 + g * 4];
    float* ob = outF + (size_t)b * C_OUT * HW + p0 + p;
    const int o0 = g * 4;
    ob[(size_t)(o0 + 0) * HW] = acc2[0][0] + bb0.x;
    ob[(size_t)(o0 + 1) * HW] = acc2[0][1] + bb0.y;
    ob[(size_t)(o0 + 2) * HW] = acc2[0][2] + bb0.z;
    ob[(size_t)(o0 + 3) * HW] = acc2[0][3] + bb0.w;
    ob[(size_t)(16 + o0 + 0) * HW] = acc2[1][0] + bb1.x;
    ob[(size_t)(16 + o0 + 1) * HW] = acc2[1][1] + bb1.y;
    ob[(size_t)(16 + o0 + 2) * HW] = acc2[1][2] + bb1.z;
    ob[(size_t)(16 + o0 + 3) * HW] = acc2[1][3] + bb1.w;
}

// ---------------- Kernel 3: partial gram of sF ----------
__global__ __launch_bounds__(256) void k_gram(const float* __restrict__ sF,
                                              float* __restrict__ partial) {
    __shared__ float sS[32 * 257];
    int b = blockIdx.y, sl = blockIdx.x;
    int t = threadIdx.x;
    const float* base = sF + (size_t)b * C_OUT * HW + sl * 1024;
    int i = t >> 3, jb = (t & 7) * 4;
    float acc[4] = {0.f, 0.f, 0.f, 0.f};
    for (int ch = 0; ch < 4; ++ch) {
        __syncthreads();
        #pragma unroll
        for (int r = 0; r < 32; ++r)
            sS[r * 257 + t] = base[(size_t)r * HW + ch * 256 + t];
        __syncthreads();
        for (int n = 0; n < 256; ++n) {
            float si = sS[i * 257 + n];
            #pragma unroll
            for (int q = 0; q < 4; ++q)
                acc[q] = fmaf(si, sS[(jb + q) * 257 + n], acc[q]);
        }
    }
    float* dst = partial + ((size_t)(b * 16 + sl)) * 1024 + t * 4;
    #pragma unroll
    for (int q = 0; q < 4; ++q) dst[q] = acc[q];
}

// ---------------- Kernel 4: reduce partials + softmax + scale ----------
__global__ __launch_bounds__(1024) void k_softmax(const float* __restrict__ partial,
                                                  float* __restrict__ scov) {
    int b = blockIdx.x;
    int j = threadIdx.x, i = threadIdx.y;
    float v = 0.f;
    #pragma unroll
    for (int s = 0; s < 16; ++s)
        v += partial[((size_t)(b * 16 + s)) * 1024 + i * 32 + j];
    v *= (1.f / (float)HW);
    float m = v;
    #pragma unroll
    for (int d = 16; d > 0; d >>= 1) m = fmaxf(m, __shfl_xor(m, d, 32));
    float e = expf(v - m);
    float sum = e;
    #pragma unroll
    for (int d = 16; d > 0; d >>= 1) sum += __shfl_xor(sum, d, 32);
    scov[(size_t)b * 1024 + i * 32 + j] = e / sum * 0.17677669529663687f;
}

// ---------------- Kernel 5: out = wu@(scov@cF) + bu + smean + content ----
__global__ __launch_bounds__(256) void k_final(const float* __restrict__ cF,
                                               const float* __restrict__ scov,
                                               const float* __restrict__ wu,
                                               const float* __restrict__ bu,
                                               const float* __restrict__ smean,
                                               const float* __restrict__ content,
                                               float* __restrict__ out) {
    __shared__ float sCov[1024];
    __shared__ float sC[32 * 64];
    __shared__ float sG[32 * 64];
    __shared__ float sWu[32 * 260];
    int t = threadIdx.x;
    int p0 = blockIdx.x * 64;
    int b = blockIdx.y;
    #pragma unroll
    for (int q = 0; q < 4; ++q) sCov[t + 256 * q] = scov[(size_t)b * 1024 + t + 256 * q];
    {
        int p = t & 63, rb = t >> 6;
        #pragma unroll
        for (int pass = 0; pass < 8; ++pass) {
            int r = pass * 4 + rb;
            sC[r * 64 + p] = cF[(size_t)b * C_OUT * HW + (size_t)r * HW + p0 + p];
        }
    }
    {
        int k = t & 31, ob = t >> 5;
        #pragma unroll
        for (int pass = 0; pass < 32; ++pass) {
            int o = pass * 8 + ob;
            sWu[k * 260 + o] = wu[o * 32 + k];
        }
    }
    __syncthreads();
    {
        int gp = t & 63, gib = (t >> 6) * 8;
        #pragma unroll
        for (int rr = 0; rr < 8; ++rr) {
            int gi = gib + rr;
            float a = 0.f;
            #pragma unroll
            for (int k = 0; k < 32; ++k)
                a = fmaf(sCov[gi * 32 + k], sC[k * 64 + gp], a);
            sG[gi * 64 + gp] = a;
        }
    }
    __syncthreads();
    int tx = t & 7, ty = t >> 3;
    float acc[8][8];
    #pragma unroll
    for (int i = 0; i < 8; ++i)
        #pragma unroll
        for (int j = 0; j < 8; ++j) acc[i][j] = 0.f;
    #pragma unroll 4
    for (int k = 0; k < 32; ++k) {
        float4 a4a = *(const float4*)&sWu[k * 260 + ty * 8];
        float4 a4b = *(const float4*)&sWu[k * 260 + ty * 8 + 4];
        float4 b4a = *(const float4*)&sG[k * 64 + tx * 8];
        float4 b4b = *(const float4*)&sG[k * 64 + tx * 8 + 4];
        float a[8] = {a4a.x, a4a.y, a4a.z, a4a.w, a4b.x, a4b.y, a4b.z, a4b.w};
        float bb[8] = {b4a.x, b4a.y, b4a.z, b4a.w, b4b.x, b4b.y, b4b.z, b4b.w};
        #pragma unroll
        for (int i = 0; i < 8; ++i)
            #pragma unroll
            for (int j = 0; j < 8; ++j)
                acc[i][j] = fmaf(a[i], bb[j], acc[i][j]);
    }
    #pragma unroll
    for (int i = 0; i < 8; ++i) {
        int o = ty * 8 + i;
        float add = bu[o] + smean[b * 256 + o];
        const float* csrc = content + (size_t)b * C_IN * HW + (size_t)o * HW + p0 + tx * 8;
        float* dst = out + (size_t)b * C_IN * HW + (size_t)o * HW + p0 + tx * 8;
        float4 c0 = *(const float4*)csrc;
        float4 c1 = *(const float4*)(csrc + 4);
        float4 r0 = make_float4(acc[i][0] + add + c0.x, acc[i][1] + add + c0.y,
                                acc[i][2] + add + c0.z, acc[i][3] + add + c0.w);
        float4 r1 = make_float4(acc[i][4] + add + c1.x, acc[i][5] + add + c1.y,
                                acc[i][6] + add + c1.z, acc[i][7] + add + c1.w);
        *(float4*)dst = r0;
        *(float4*)(dst + 4) = r1;
    }
}

extern "C" void kernel_launch(void* const* d_in, const int* in_sizes, int n_in,
                              void* d_out, int out_size, void* d_ws, size_t ws_size,
                              hipStream_t stream) {
    const float* content = (const float*)d_in[0];
    const float* style   = (const float*)d_in[1];
    const float* w1      = (const float*)d_in[2];
    const float* b1      = (const float*)d_in[3];
    const float* w2      = (const float*)d_in[4];
    const float* b2      = (const float*)d_in[5];
    const float* wu      = (const float*)d_in[6];
    const float* bu      = (const float*)d_in[7];
    float* out = (float*)d_out;
    float* ws  = (float*)d_ws;

    // ws layout (floats). Aliasing is ordering-safe:
    //  - W2b/bias1c/bias1s alias the scov region (scov written later by k_softmax)
    //  - W1c aliases the partial region (partial written later by k_gram)
    float* cmean   = ws;                         // 2048
    float* crstd   = ws + 2048;                  // 2048
    float* smean   = ws + 4096;                  // 2048
    float* scov    = ws + 6144;                  // 8192 (live: softmax->final)
    __bf16* W2b    = (__bf16*)(ws + 6144);       // 4096 bf16 (dead before scov written)
    float* bias1c  = ws + 8192;                  // 1024
    float* bias1s  = ws + 9216;                  // 1024
    float* partial = ws + 14336;                 // 131072 (live: gram->softmax)
    __bf16* W1c    = (__bf16*)(ws + 14336);      // 262144 bf16 (dead before partial written)
    __bf16* W1s    = (__bf16*)(ws + 145408);     // 32768 bf16
    float* cF      = ws + 161792;                // 4194304
    float* sF      = cF + 4194304;               // 4194304

    k_stats<<<dim3(2048), 256, 0, stream>>>(content, style, cmean, crstd, smean);
    k_wprep<<<dim3(128, 8), 256, 0, stream>>>(w1, b1, cmean, crstd, smean,
                                              W1c, bias1c, W1s, bias1s);
    k_w2prep<<<dim3(16), 256, 0, stream>>>(w2, W2b);
    k_net_mfma<<<dim3(256, 8), 256, 0, stream>>>(content, W1c, bias1c, W2b, b2, cF, 1);
    k_net_mfma<<<dim3(256, 8), 256, 0, stream>>>(style, W1s, bias1s, W2b, b2, sF, 0);
    k_gram<<<dim3(16, 8), 256, 0, stream>>>(sF, partial);
    k_softmax<<<dim3(8), dim3(32, 32), 0, stream>>>(partial, scov);
    k_final<<<dim3(256, 8), 256, 0, stream>>>(cF, scov, wu, bu, smean, content, out);
}

// Round 5
// 247.403 us; speedup vs baseline: 2.3619x; 1.0292x over previous
//
#include <hip/hip_runtime.h>

#define HW 16384
#define C_IN 256
#define C_MID 128
#define C_OUT 32
#define EPSF 1e-5f

typedef __bf16 bf16x8 __attribute__((ext_vector_type(8)));
typedef __bf16 bf16x4 __attribute__((ext_vector_type(4)));
typedef float f32x4 __attribute__((ext_vector_type(4)));

// ---------------- Kernel 1: per-(b,c) stats (split streams, reg-hoisted) ----
// blocks 0..2047: content plane bc -> cmean, crstd
// blocks 2048..4095: style plane bc -> smean
__global__ __launch_bounds__(256) void k_stats2(const float* __restrict__ content,
                                                const float* __restrict__ style,
                                                float* __restrict__ cmean,
                                                float* __restrict__ crstd,
                                                float* __restrict__ smean) {
    const int id = blockIdx.x;
    const bool is_c = id < 2048;
    const int bc = is_c ? id : id - 2048;
    const float4* p = (const float4*)((is_c ? content : style) + (size_t)bc * HW);
    const int t = threadIdx.x;

    float4 v[16];
    #pragma unroll
    for (int i = 0; i < 16; ++i) v[i] = p[t + 256 * i];

    float s = 0.f, q = 0.f;
    #pragma unroll
    for (int i = 0; i < 16; ++i) {
        s += (v[i].x + v[i].y) + (v[i].z + v[i].w);
        q += (v[i].x * v[i].x + v[i].y * v[i].y) + (v[i].z * v[i].z + v[i].w * v[i].w);
    }
    // wave reduce (64 lanes)
    #pragma unroll
    for (int d = 32; d > 0; d >>= 1) {
        s += __shfl_xor(s, d, 64);
        q += __shfl_xor(q, d, 64);
    }
    __shared__ float red[8];
    const int wv = t >> 6;
    if ((t & 63) == 0) { red[wv] = s; red[4 + wv] = q; }
    __syncthreads();
    if (t == 0) {
        float S = (red[0] + red[1]) + (red[2] + red[3]);
        float n = (float)HW;
        if (is_c) {
            float Q = (red[4] + red[5]) + (red[6] + red[7]);
            float var = (Q - S * S / n) / (n - 1.f);
            cmean[bc] = S / n;
            crstd[bc] = 1.f / sqrtf(var + EPSF);
        } else {
            smean[bc] = S / n;
        }
    }
}

// ---------------- Prep: fold norm into conv1 weights (bf16) ----------------
__global__ __launch_bounds__(256) void k_wprep(const float* __restrict__ w1,
                                               const float* __restrict__ b1,
                                               const float* __restrict__ cmean,
                                               const float* __restrict__ crstd,
                                               const float* __restrict__ smean,
                                               __bf16* __restrict__ W1c,
                                               float* __restrict__ bias1c,
                                               __bf16* __restrict__ W1s,
                                               float* __restrict__ bias1s) {
    int o = blockIdx.x, b = blockIdx.y, t = threadIdx.x;
    float w = w1[o * 256 + t];
    float r = crstd[b * 256 + t];
    float wc = w * r;
    W1c[((size_t)(b * 128 + o)) * 256 + t] = (__bf16)wc;
    if (b == 0) W1s[o * 256 + t] = (__bf16)w;
    float pc = wc * cmean[b * 256 + t];
    float ps = w * smean[b * 256 + t];
    __shared__ float rA[256], rB[256];
    rA[t] = pc; rB[t] = ps;
    __syncthreads();
    for (int off = 128; off > 0; off >>= 1) {
        if (t < off) { rA[t] += rA[t + off]; rB[t] += rB[t + off]; }
        __syncthreads();
    }
    if (t == 0) {
        bias1c[b * 128 + o] = b1[o] - rA[0];
        bias1s[b * 128 + o] = b1[o] - rB[0];
    }
}

__global__ __launch_bounds__(256) void k_w2prep(const float* __restrict__ w2,
                                                __bf16* __restrict__ W2b) {
    int i = blockIdx.x * 256 + threadIdx.x;   // 4096 total
    if (i < 4096) W2b[i] = (__bf16)w2[i];
}

// ---------------- Kernel 2: MFMA fused net ----------------
__global__ __launch_bounds__(256) void k_net_mfma(const float* __restrict__ x,
                                                  const __bf16* __restrict__ W1,
                                                  const float* __restrict__ bias1,
                                                  const __bf16* __restrict__ W2,
                                                  const float* __restrict__ b2,
                                                  float* __restrict__ outF,
                                                  int w1_per_batch) {
    __shared__ __bf16 Xl[64 * 256];   // 32 KB, [p][c] swizzled
    __shared__ __bf16 Tl[64 * 128];   // 16 KB, [p][o] swizzled
    const int tid = threadIdx.x;
    const int l = tid & 63, wv = tid >> 6;
    const int lr = l & 15, g = l >> 4;
    const int sw = (lr & 7) << 4;
    const int p0 = blockIdx.x * 64;
    const int b = blockIdx.y;
    const float* xb = x + (size_t)b * C_IN * HW;

    // ---- stage X[c][p] (global f32) -> Xl[p][c] (bf16, swizzled)
    {
        const int p = wv * 16 + lr;
        const float* xp = xb + p0 + p;
        char* row = (char*)&Xl[p * 256];
        #pragma unroll 4
        for (int cc = 0; cc < 16; ++cc) {
            const int c = cc * 16 + g * 4;
            float f0 = xp[(size_t)(c + 0) * HW];
            float f1 = xp[(size_t)(c + 1) * HW];
            float f2 = xp[(size_t)(c + 2) * HW];
            float f3 = xp[(size_t)(c + 3) * HW];
            bf16x4 v;
            v[0] = (__bf16)f0; v[1] = (__bf16)f1; v[2] = (__bf16)f2; v[3] = (__bf16)f3;
            *(bf16x4*)(row + ((c * 2) ^ sw)) = v;
        }
    }
    __syncthreads();

    const f32x4 zero4 = {0.f, 0.f, 0.f, 0.f};
    f32x4 acc[2][4];
    #pragma unroll
    for (int mt = 0; mt < 2; ++mt)
        #pragma unroll
        for (int nt = 0; nt < 4; ++nt) acc[mt][nt] = zero4;

    const __bf16* W1b = W1 + (w1_per_batch ? ((size_t)b << 15) : 0);
    const __bf16* wrow0 = W1b + (size_t)(wv * 32 + lr) * 256 + g * 8;
    const __bf16* wrow1 = wrow0 + 16 * 256;

    #pragma unroll
    for (int kt = 0; kt < 8; ++kt) {
        bf16x8 a0 = *(const bf16x8*)(wrow0 + kt * 32);
        bf16x8 a1 = *(const bf16x8*)(wrow1 + kt * 32);
        #pragma unroll
        for (int nt = 0; nt < 4; ++nt) {
            const char* xrow = (const char*)&Xl[(nt * 16 + lr) * 256];
            bf16x8 bfr = *(const bf16x8*)(xrow + (((kt * 32 + g * 8) * 2) ^ sw));
            acc[0][nt] = __builtin_amdgcn_mfma_f32_16x16x32_bf16(a0, bfr, acc[0][nt], 0, 0, 0);
            acc[1][nt] = __builtin_amdgcn_mfma_f32_16x16x32_bf16(a1, bfr, acc[1][nt], 0, 0, 0);
        }
    }

    float4 bia[2];
    bia[0] = *(const float4*)&bias1[b * 128 + wv * 32 + g * 4];
    bia[1] = *(const float4*)&bias1[b * 128 + wv * 32 + 16 + g * 4];
    #pragma unroll
    for (int mt = 0; mt < 2; ++mt) {
        #pragma unroll
        for (int nt = 0; nt < 4; ++nt) {
            const int p = nt * 16 + lr;
            char* trow = (char*)&Tl[p * 128];
            const int ob = (wv * 32 + mt * 16 + g * 4) * 2;
            bf16x4 tv;
            tv[0] = (__bf16)fmaxf(acc[mt][nt][0] + bia[mt].x, 0.f);
            tv[1] = (__bf16)fmaxf(acc[mt][nt][1] + bia[mt].y, 0.f);
            tv[2] = (__bf16)fmaxf(acc[mt][nt][2] + bia[mt].z, 0.f);
            tv[3] = (__bf16)fmaxf(acc[mt][nt][3] + bia[mt].w, 0.f);
            *(bf16x4*)(trow + (ob ^ sw)) = tv;
        }
    }
    __syncthreads();

    f32x4 acc2[2];
    acc2[0] = zero4; acc2[1] = zero4;
    const int p = wv * 16 + lr;
    const char* trow = (const char*)&Tl[p * 128];
    const __bf16* w2r0 = W2 + (size_t)lr * 128 + g * 8;
    const __bf16* w2r1 = w2r0 + 16 * 128;
    #pragma unroll
    for (int kt = 0; kt < 4; ++kt) {
        bf16x8 bfr = *(const bf16x8*)(trow + (((kt * 32 + g * 8) * 2) ^ sw));
        bf16x8 a0 = *(const bf16x8*)(w2r0 + kt * 32);
        bf16x8 a1 = *(const bf16x8*)(w2r1 + kt * 32);
        acc2[0] = __builtin_amdgcn_mfma_f32_16x16x32_bf16(a0, bfr, acc2[0], 0, 0, 0);
        acc2[1] = __builtin_amdgcn_mfma_f32_16x16x32_bf16(a1, bfr, acc2[1], 0, 0, 0);
    }
    float4 bb0 = *(const float4*)&b2[g * 4];
    float4 bb1 = *(const float4*)&b2[16 + g * 4];
    float* ob = outF + (size_t)b * C_OUT * HW + p0 + p;
    const int o0 = g * 4;
    ob[(size_t)(o0 + 0) * HW] = acc2[0][0] + bb0.x;
    ob[(size_t)(o0 + 1) * HW] = acc2[0][1] + bb0.y;
    ob[(size_t)(o0 + 2) * HW] = acc2[0][2] + bb0.z;
    ob[(size_t)(o0 + 3) * HW] = acc2[0][3] + bb0.w;
    ob[(size_t)(16 + o0 + 0) * HW] = acc2[1][0] + bb1.x;
    ob[(size_t)(16 + o0 + 1) * HW] = acc2[1][1] + bb1.y;
    ob[(size_t)(16 + o0 + 2) * HW] = acc2[1][2] + bb1.z;
    ob[(size_t)(16 + o0 + 3) * HW] = acc2[1][3] + bb1.w;
}

// ---------------- Kernel 3: partial gram of sF ----------
__global__ __launch_bounds__(256) void k_gram(const float* __restrict__ sF,
                                              float* __restrict__ partial) {
    __shared__ float sS[32 * 257];
    int b = blockIdx.y, sl = blockIdx.x;
    int t = threadIdx.x;
    const float* base = sF + (size_t)b * C_OUT * HW + sl * 1024;
    int i = t >> 3, jb = (t & 7) * 4;
    float acc[4] = {0.f, 0.f, 0.f, 0.f};
    for (int ch = 0; ch < 4; ++ch) {
        __syncthreads();
        #pragma unroll
        for (int r = 0; r < 32; ++r)
            sS[r * 257 + t] = base[(size_t)r * HW + ch * 256 + t];
        __syncthreads();
        for (int n = 0; n < 256; ++n) {
            float si = sS[i * 257 + n];
            #pragma unroll
            for (int q = 0; q < 4; ++q)
                acc[q] = fmaf(si, sS[(jb + q) * 257 + n], acc[q]);
        }
    }
    float* dst = partial + ((size_t)(b * 16 + sl)) * 1024 + t * 4;
    #pragma unroll
    for (int q = 0; q < 4; ++q) dst[q] = acc[q];
}

// ---------------- Kernel 4: reduce partials + softmax + scale ----------
__global__ __launch_bounds__(1024) void k_softmax(const float* __restrict__ partial,
                                                  float* __restrict__ scov) {
    int b = blockIdx.x;
    int j = threadIdx.x, i = threadIdx.y;
    float v = 0.f;
    #pragma unroll
    for (int s = 0; s < 16; ++s)
        v += partial[((size_t)(b * 16 + s)) * 1024 + i * 32 + j];
    v *= (1.f / (float)HW);
    float m = v;
    #pragma unroll
    for (int d = 16; d > 0; d >>= 1) m = fmaxf(m, __shfl_xor(m, d, 32));
    float e = expf(v - m);
    float sum = e;
    #pragma unroll
    for (int d = 16; d > 0; d >>= 1) sum += __shfl_xor(sum, d, 32);
    scov[(size_t)b * 1024 + i * 32 + j] = e / sum * 0.17677669529663687f;
}

// ---------------- Kernel 5: out = wu@(scov@cF) + bu + smean + content ----
__global__ __launch_bounds__(256) void k_final(const float* __restrict__ cF,
                                               const float* __restrict__ scov,
                                               const float* __restrict__ wu,
                                               const float* __restrict__ bu,
                                               const float* __restrict__ smean,
                                               const float* __restrict__ content,
                                               float* __restrict__ out) {
    __shared__ float sCov[1024];
    __shared__ float sC[32 * 64];
    __shared__ float sG[32 * 64];
    __shared__ float sWu[32 * 260];
    int t = threadIdx.x;
    int p0 = blockIdx.x * 64;
    int b = blockIdx.y;
    #pragma unroll
    for (int q = 0; q < 4; ++q) sCov[t + 256 * q] = scov[(size_t)b * 1024 + t + 256 * q];
    {
        int p = t & 63, rb = t >> 6;
        #pragma unroll
        for (int pass = 0; pass < 8; ++pass) {
            int r = pass * 4 + rb;
            sC[r * 64 + p] = cF[(size_t)b * C_OUT * HW + (size_t)r * HW + p0 + p];
        }
    }
    {
        int k = t & 31, ob = t >> 5;
        #pragma unroll
        for (int pass = 0; pass < 32; ++pass) {
            int o = pass * 8 + ob;
            sWu[k * 260 + o] = wu[o * 32 + k];
        }
    }
    __syncthreads();
    {
        int gp = t & 63, gib = (t >> 6) * 8;
        #pragma unroll
        for (int rr = 0; rr < 8; ++rr) {
            int gi = gib + rr;
            float a = 0.f;
            #pragma unroll
            for (int k = 0; k < 32; ++k)
                a = fmaf(sCov[gi * 32 + k], sC[k * 64 + gp], a);
            sG[gi * 64 + gp] = a;
        }
    }
    __syncthreads();
    int tx = t & 7, ty = t >> 3;
    float acc[8][8];
    #pragma unroll
    for (int i = 0; i < 8; ++i)
        #pragma unroll
        for (int j = 0; j < 8; ++j) acc[i][j] = 0.f;
    #pragma unroll 4
    for (int k = 0; k < 32; ++k) {
        float4 a4a = *(const float4*)&sWu[k * 260 + ty * 8];
        float4 a4b = *(const float4*)&sWu[k * 260 + ty * 8 + 4];
        float4 b4a = *(const float4*)&sG[k * 64 + tx * 8];
        float4 b4b = *(const float4*)&sG[k * 64 + tx * 8 + 4];
        float a[8] = {a4a.x, a4a.y, a4a.z, a4a.w, a4b.x, a4b.y, a4b.z, a4b.w};
        float bb[8] = {b4a.x, b4a.y, b4a.z, b4a.w, b4b.x, b4b.y, b4b.z, b4b.w};
        #pragma unroll
        for (int i = 0; i < 8; ++i)
            #pragma unroll
            for (int j = 0; j < 8; ++j)
                acc[i][j] = fmaf(a[i], bb[j], acc[i][j]);
    }
    #pragma unroll
    for (int i = 0; i < 8; ++i) {
        int o = ty * 8 + i;
        float add = bu[o] + smean[b * 256 + o];
        const float* csrc = content + (size_t)b * C_IN * HW + (size_t)o * HW + p0 + tx * 8;
        float* dst = out + (size_t)b * C_IN * HW + (size_t)o * HW + p0 + tx * 8;
        float4 c0 = *(const float4*)csrc;
        float4 c1 = *(const float4*)(csrc + 4);
        f32x4 r0 = {acc[i][0] + add + c0.x, acc[i][1] + add + c0.y,
                    acc[i][2] + add + c0.z, acc[i][3] + add + c0.w};
        f32x4 r1 = {acc[i][4] + add + c1.x, acc[i][5] + add + c1.y,
                    acc[i][6] + add + c1.z, acc[i][7] + add + c1.w};
        __builtin_nontemporal_store(r0, (f32x4*)dst);
        __builtin_nontemporal_store(r1, (f32x4*)(dst + 4));
    }
}

extern "C" void kernel_launch(void* const* d_in, const int* in_sizes, int n_in,
                              void* d_out, int out_size, void* d_ws, size_t ws_size,
                              hipStream_t stream) {
    const float* content = (const float*)d_in[0];
    const float* style   = (const float*)d_in[1];
    const float* w1      = (const float*)d_in[2];
    const float* b1      = (const float*)d_in[3];
    const float* w2      = (const float*)d_in[4];
    const float* b2      = (const float*)d_in[5];
    const float* wu      = (const float*)d_in[6];
    const float* bu      = (const float*)d_in[7];
    float* out = (float*)d_out;
    float* ws  = (float*)d_ws;

    float* cmean   = ws;                         // 2048
    float* crstd   = ws + 2048;                  // 2048
    float* smean   = ws + 4096;                  // 2048
    float* scov    = ws + 6144;                  // 8192 (live: softmax->final)
    __bf16* W2b    = (__bf16*)(ws + 6144);       // 4096 bf16 (dead before scov written)
    float* bias1c  = ws + 8192;                  // 1024
    float* bias1s  = ws + 9216;                  // 1024
    float* partial = ws + 14336;                 // 131072 (live: gram->softmax)
    __bf16* W1c    = (__bf16*)(ws + 14336);      // 262144 bf16 (dead before partial written)
    __bf16* W1s    = (__bf16*)(ws + 145408);     // 32768 bf16
    float* cF      = ws + 161792;                // 4194304
    float* sF      = cF + 4194304;               // 4194304

    k_stats2<<<dim3(4096), 256, 0, stream>>>(content, style, cmean, crstd, smean);
    k_wprep<<<dim3(128, 8), 256, 0, stream>>>(w1, b1, cmean, crstd, smean,
                                              W1c, bias1c, W1s, bias1s);
    k_w2prep<<<dim3(16), 256, 0, stream>>>(w2, W2b);
    k_net_mfma<<<dim3(256, 8), 256, 0, stream>>>(content, W1c, bias1c, W2b, b2, cF, 1);
    k_net_mfma<<<dim3(256, 8), 256, 0, stream>>>(style, W1s, bias1s, W2b, b2, sF, 0);
    k_gram<<<dim3(16, 8), 256, 0, stream>>>(sF, partial);
    k_softmax<<<dim3(8), dim3(32, 32), 0, stream>>>(partial, scov);
    k_final<<<dim3(256, 8), 256, 0, stream>>>(cF, scov, wu, bu, smean, content, out);
}

// Round 6
// 246.843 us; speedup vs baseline: 2.3673x; 1.0023x over previous
//
#include <hip/hip_runtime.h>

#define HW 16384
#define C_IN 256
#define C_MID 128
#define C_OUT 32
#define EPSF 1e-5f

typedef __bf16 bf16x8 __attribute__((ext_vector_type(8)));
typedef __bf16 bf16x4 __attribute__((ext_vector_type(4)));
typedef float f32x4 __attribute__((ext_vector_type(4)));

// ---------------- Kernel 1: per-(b,c) stats (high-TLP version) ----------
// 1024 threads (16 waves) per block, one plane per block.
// blocks 0..2047: content plane -> cmean, crstd ; 2048..4095: style -> smean
__global__ __launch_bounds__(1024) void k_stats3(const float* __restrict__ content,
                                                 const float* __restrict__ style,
                                                 float* __restrict__ cmean,
                                                 float* __restrict__ crstd,
                                                 float* __restrict__ smean) {
    const int id = blockIdx.x;
    const bool is_c = id < 2048;
    const int bc = is_c ? id : id - 2048;
    const float4* p = (const float4*)((is_c ? content : style) + (size_t)bc * HW);
    const int t = threadIdx.x;

    // 4 independent float4 loads (16 VGPR payload), consumed after issue
    float4 v0 = p[t];
    float4 v1 = p[t + 1024];
    float4 v2 = p[t + 2048];
    float4 v3 = p[t + 3072];

    float s0 = (v0.x + v0.y) + (v0.z + v0.w);
    float s1 = (v1.x + v1.y) + (v1.z + v1.w);
    float s2 = (v2.x + v2.y) + (v2.z + v2.w);
    float s3 = (v3.x + v3.y) + (v3.z + v3.w);
    float q0 = (v0.x * v0.x + v0.y * v0.y) + (v0.z * v0.z + v0.w * v0.w);
    float q1 = (v1.x * v1.x + v1.y * v1.y) + (v1.z * v1.z + v1.w * v1.w);
    float q2 = (v2.x * v2.x + v2.y * v2.y) + (v2.z * v2.z + v2.w * v2.w);
    float q3 = (v3.x * v3.x + v3.y * v3.y) + (v3.z * v3.z + v3.w * v3.w);
    float s = (s0 + s1) + (s2 + s3);
    float q = (q0 + q1) + (q2 + q3);

    #pragma unroll
    for (int d = 32; d > 0; d >>= 1) {
        s += __shfl_xor(s, d, 64);
        q += __shfl_xor(q, d, 64);
    }
    __shared__ float rs[16], rq[16];
    const int wv = t >> 6;
    if ((t & 63) == 0) { rs[wv] = s; rq[wv] = q; }
    __syncthreads();
    if (t < 16) {
        s = rs[t]; q = rq[t];
        #pragma unroll
        for (int d = 8; d > 0; d >>= 1) {
            s += __shfl_xor(s, d, 16);
            q += __shfl_xor(q, d, 16);
        }
        if (t == 0) {
            float n = (float)HW;
            if (is_c) {
                float var = (q - s * s / n) / (n - 1.f);
                cmean[bc] = s / n;
                crstd[bc] = 1.f / sqrtf(var + EPSF);
            } else {
                smean[bc] = s / n;
            }
        }
    }
}

// ---------------- Prep: fold norm into conv1 weights (bf16) ----------------
__global__ __launch_bounds__(256) void k_wprep(const float* __restrict__ w1,
                                               const float* __restrict__ b1,
                                               const float* __restrict__ cmean,
                                               const float* __restrict__ crstd,
                                               const float* __restrict__ smean,
                                               __bf16* __restrict__ W1c,
                                               float* __restrict__ bias1c,
                                               __bf16* __restrict__ W1s,
                                               float* __restrict__ bias1s) {
    int o = blockIdx.x, b = blockIdx.y, t = threadIdx.x;
    float w = w1[o * 256 + t];
    float r = crstd[b * 256 + t];
    float wc = w * r;
    W1c[((size_t)(b * 128 + o)) * 256 + t] = (__bf16)wc;
    if (b == 0) W1s[o * 256 + t] = (__bf16)w;
    float pc = wc * cmean[b * 256 + t];
    float ps = w * smean[b * 256 + t];
    __shared__ float rA[256], rB[256];
    rA[t] = pc; rB[t] = ps;
    __syncthreads();
    for (int off = 128; off > 0; off >>= 1) {
        if (t < off) { rA[t] += rA[t + off]; rB[t] += rB[t + off]; }
        __syncthreads();
    }
    if (t == 0) {
        bias1c[b * 128 + o] = b1[o] - rA[0];
        bias1s[b * 128 + o] = b1[o] - rB[0];
    }
}

__global__ __launch_bounds__(256) void k_w2prep(const float* __restrict__ w2,
                                                __bf16* __restrict__ W2b) {
    int i = blockIdx.x * 256 + threadIdx.x;   // 4096 total
    if (i < 4096) W2b[i] = (__bf16)w2[i];
}

// ---------------- Kernel 2: MFMA fused net ----------------
__global__ __launch_bounds__(256) void k_net_mfma(const float* __restrict__ x,
                                                  const __bf16* __restrict__ W1,
                                                  const float* __restrict__ bias1,
                                                  const __bf16* __restrict__ W2,
                                                  const float* __restrict__ b2,
                                                  float* __restrict__ outF,
                                                  int w1_per_batch) {
    __shared__ __bf16 Xl[64 * 256];   // 32 KB, [p][c] swizzled
    __shared__ __bf16 Tl[64 * 128];   // 16 KB, [p][o] swizzled
    const int tid = threadIdx.x;
    const int l = tid & 63, wv = tid >> 6;
    const int lr = l & 15, g = l >> 4;
    const int sw = (lr & 7) << 4;
    const int p0 = blockIdx.x * 64;
    const int b = blockIdx.y;
    const float* xb = x + (size_t)b * C_IN * HW;

    // ---- stage X[c][p] (global f32) -> Xl[p][c] (bf16, swizzled)
    {
        const int p = wv * 16 + lr;
        const float* xp = xb + p0 + p;
        char* row = (char*)&Xl[p * 256];
        #pragma unroll 4
        for (int cc = 0; cc < 16; ++cc) {
            const int c = cc * 16 + g * 4;
            float f0 = xp[(size_t)(c + 0) * HW];
            float f1 = xp[(size_t)(c + 1) * HW];
            float f2 = xp[(size_t)(c + 2) * HW];
            float f3 = xp[(size_t)(c + 3) * HW];
            bf16x4 v;
            v[0] = (__bf16)f0; v[1] = (__bf16)f1; v[2] = (__bf16)f2; v[3] = (__bf16)f3;
            *(bf16x4*)(row + ((c * 2) ^ sw)) = v;
        }
    }
    __syncthreads();

    const f32x4 zero4 = {0.f, 0.f, 0.f, 0.f};
    f32x4 acc[2][4];
    #pragma unroll
    for (int mt = 0; mt < 2; ++mt)
        #pragma unroll
        for (int nt = 0; nt < 4; ++nt) acc[mt][nt] = zero4;

    const __bf16* W1b = W1 + (w1_per_batch ? ((size_t)b << 15) : 0);
    const __bf16* wrow0 = W1b + (size_t)(wv * 32 + lr) * 256 + g * 8;
    const __bf16* wrow1 = wrow0 + 16 * 256;

    #pragma unroll
    for (int kt = 0; kt < 8; ++kt) {
        bf16x8 a0 = *(const bf16x8*)(wrow0 + kt * 32);
        bf16x8 a1 = *(const bf16x8*)(wrow1 + kt * 32);
        #pragma unroll
        for (int nt = 0; nt < 4; ++nt) {
            const char* xrow = (const char*)&Xl[(nt * 16 + lr) * 256];
            bf16x8 bfr = *(const bf16x8*)(xrow + (((kt * 32 + g * 8) * 2) ^ sw));
            acc[0][nt] = __builtin_amdgcn_mfma_f32_16x16x32_bf16(a0, bfr, acc[0][nt], 0, 0, 0);
            acc[1][nt] = __builtin_amdgcn_mfma_f32_16x16x32_bf16(a1, bfr, acc[1][nt], 0, 0, 0);
        }
    }

    float4 bia[2];
    bia[0] = *(const float4*)&bias1[b * 128 + wv * 32 + g * 4];
    bia[1] = *(const float4*)&bias1[b * 128 + wv * 32 + 16 + g * 4];
    #pragma unroll
    for (int mt = 0; mt < 2; ++mt) {
        #pragma unroll
        for (int nt = 0; nt < 4; ++nt) {
            const int p = nt * 16 + lr;
            char* trow = (char*)&Tl[p * 128];
            const int ob = (wv * 32 + mt * 16 + g * 4) * 2;
            bf16x4 tv;
            tv[0] = (__bf16)fmaxf(acc[mt][nt][0] + bia[mt].x, 0.f);
            tv[1] = (__bf16)fmaxf(acc[mt][nt][1] + bia[mt].y, 0.f);
            tv[2] = (__bf16)fmaxf(acc[mt][nt][2] + bia[mt].z, 0.f);
            tv[3] = (__bf16)fmaxf(acc[mt][nt][3] + bia[mt].w, 0.f);
            *(bf16x4*)(trow + (ob ^ sw)) = tv;
        }
    }
    __syncthreads();

    f32x4 acc2[2];
    acc2[0] = zero4; acc2[1] = zero4;
    const int p = wv * 16 + lr;
    const char* trow = (const char*)&Tl[p * 128];
    const __bf16* w2r0 = W2 + (size_t)lr * 128 + g * 8;
    const __bf16* w2r1 = w2r0 + 16 * 128;
    #pragma unroll
    for (int kt = 0; kt < 4; ++kt) {
        bf16x8 bfr = *(const bf16x8*)(trow + (((kt * 32 + g * 8) * 2) ^ sw));
        bf16x8 a0 = *(const bf16x8*)(w2r0 + kt * 32);
        bf16x8 a1 = *(const bf16x8*)(w2r1 + kt * 32);
        acc2[0] = __builtin_amdgcn_mfma_f32_16x16x32_bf16(a0, bfr, acc2[0], 0, 0, 0);
        acc2[1] = __builtin_amdgcn_mfma_f32_16x16x32_bf16(a1, bfr, acc2[1], 0, 0, 0);
    }
    float4 bb0 = *(const float4*)&b2[g * 4];
    float4 bb1 = *(const float4*)&b2[16 + g * 4];
    float* ob = outF + (size_t)b * C_OUT * HW + p0 + p;
    const int o0 = g * 4;
    ob[(size_t)(o0 + 0) * HW] = acc2[0][0] + bb0.x;
    ob[(size_t)(o0 + 1) * HW] = acc2[0][1] + bb0.y;
    ob[(size_t)(o0 + 2) * HW] = acc2[0][2] + bb0.z;
    ob[(size_t)(o0 + 3) * HW] = acc2[0][3] + bb0.w;
    ob[(size_t)(16 + o0 + 0) * HW] = acc2[1][0] + bb1.x;
    ob[(size_t)(16 + o0 + 1) * HW] = acc2[1][1] + bb1.y;
    ob[(size_t)(16 + o0 + 2) * HW] = acc2[1][2] + bb1.z;
    ob[(size_t)(16 + o0 + 3) * HW] = acc2[1][3] + bb1.w;
}

// ---------------- Kernel 3: partial gram of sF ----------
__global__ __launch_bounds__(256) void k_gram(const float* __restrict__ sF,
                                              float* __restrict__ partial) {
    __shared__ float sS[32 * 257];
    int b = blockIdx.y, sl = blockIdx.x;
    int t = threadIdx.x;
    const float* base = sF + (size_t)b * C_OUT * HW + sl * 1024;
    int i = t >> 3, jb = (t & 7) * 4;
    float acc[4] = {0.f, 0.f, 0.f, 0.f};
    for (int ch = 0; ch < 4; ++ch) {
        __syncthreads();
        #pragma unroll
        for (int r = 0; r < 32; ++r)
            sS[r * 257 + t] = base[(size_t)r * HW + ch * 256 + t];
        __syncthreads();
        for (int n = 0; n < 256; ++n) {
            float si = sS[i * 257 + n];
            #pragma unroll
            for (int q = 0; q < 4; ++q)
                acc[q] = fmaf(si, sS[(jb + q) * 257 + n], acc[q]);
        }
    }
    float* dst = partial + ((size_t)(b * 16 + sl)) * 1024 + t * 4;
    #pragma unroll
    for (int q = 0; q < 4; ++q) dst[q] = acc[q];
}

// ---------------- Kernel 4: reduce partials + softmax + scale ----------
__global__ __launch_bounds__(1024) void k_softmax(const float* __restrict__ partial,
                                                  float* __restrict__ scov) {
    int b = blockIdx.x;
    int j = threadIdx.x, i = threadIdx.y;
    float v = 0.f;
    #pragma unroll
    for (int s = 0; s < 16; ++s)
        v += partial[((size_t)(b * 16 + s)) * 1024 + i * 32 + j];
    v *= (1.f / (float)HW);
    float m = v;
    #pragma unroll
    for (int d = 16; d > 0; d >>= 1) m = fmaxf(m, __shfl_xor(m, d, 32));
    float e = expf(v - m);
    float sum = e;
    #pragma unroll
    for (int d = 16; d > 0; d >>= 1) sum += __shfl_xor(sum, d, 32);
    scov[(size_t)b * 1024 + i * 32 + j] = e / sum * 0.17677669529663687f;
}

// ---------------- Kernel 5: out = wu@(scov@cF) + bu + smean + content ----
__global__ __launch_bounds__(256) void k_final(const float* __restrict__ cF,
                                               const float* __restrict__ scov,
                                               const float* __restrict__ wu,
                                               const float* __restrict__ bu,
                                               const float* __restrict__ smean,
                                               const float* __restrict__ content,
                                               float* __restrict__ out) {
    __shared__ float sCov[1024];
    __shared__ float sC[32 * 64];
    __shared__ float sG[32 * 64];
    __shared__ float sWu[32 * 260];
    int t = threadIdx.x;
    int p0 = blockIdx.x * 64;
    int b = blockIdx.y;
    #pragma unroll
    for (int q = 0; q < 4; ++q) sCov[t + 256 * q] = scov[(size_t)b * 1024 + t + 256 * q];
    {
        int p = t & 63, rb = t >> 6;
        #pragma unroll
        for (int pass = 0; pass < 8; ++pass) {
            int r = pass * 4 + rb;
            sC[r * 64 + p] = cF[(size_t)b * C_OUT * HW + (size_t)r * HW + p0 + p];
        }
    }
    {
        int k = t & 31, ob = t >> 5;
        #pragma unroll
        for (int pass = 0; pass < 32; ++pass) {
            int o = pass * 8 + ob;
            sWu[k * 260 + o] = wu[o * 32 + k];
        }
    }
    __syncthreads();
    {
        int gp = t & 63, gib = (t >> 6) * 8;
        #pragma unroll
        for (int rr = 0; rr < 8; ++rr) {
            int gi = gib + rr;
            float a = 0.f;
            #pragma unroll
            for (int k = 0; k < 32; ++k)
                a = fmaf(sCov[gi * 32 + k], sC[k * 64 + gp], a);
            sG[gi * 64 + gp] = a;
        }
    }
    __syncthreads();
    int tx = t & 7, ty = t >> 3;
    float acc[8][8];
    #pragma unroll
    for (int i = 0; i < 8; ++i)
        #pragma unroll
        for (int j = 0; j < 8; ++j) acc[i][j] = 0.f;
    #pragma unroll 4
    for (int k = 0; k < 32; ++k) {
        float4 a4a = *(const float4*)&sWu[k * 260 + ty * 8];
        float4 a4b = *(const float4*)&sWu[k * 260 + ty * 8 + 4];
        float4 b4a = *(const float4*)&sG[k * 64 + tx * 8];
        float4 b4b = *(const float4*)&sG[k * 64 + tx * 8 + 4];
        float a[8] = {a4a.x, a4a.y, a4a.z, a4a.w, a4b.x, a4b.y, a4b.z, a4b.w};
        float bb[8] = {b4a.x, b4a.y, b4a.z, b4a.w, b4b.x, b4b.y, b4b.z, b4b.w};
        #pragma unroll
        for (int i = 0; i < 8; ++i)
            #pragma unroll
            for (int j = 0; j < 8; ++j)
                acc[i][j] = fmaf(a[i], bb[j], acc[i][j]);
    }
    #pragma unroll
    for (int i = 0; i < 8; ++i) {
        int o = ty * 8 + i;
        float add = bu[o] + smean[b * 256 + o];
        const float* csrc = content + (size_t)b * C_IN * HW + (size_t)o * HW + p0 + tx * 8;
        float* dst = out + (size_t)b * C_IN * HW + (size_t)o * HW + p0 + tx * 8;
        float4 c0 = *(const float4*)csrc;
        float4 c1 = *(const float4*)(csrc + 4);
        f32x4 r0 = {acc[i][0] + add + c0.x, acc[i][1] + add + c0.y,
                    acc[i][2] + add + c0.z, acc[i][3] + add + c0.w};
        f32x4 r1 = {acc[i][4] + add + c1.x, acc[i][5] + add + c1.y,
                    acc[i][6] + add + c1.z, acc[i][7] + add + c1.w};
        __builtin_nontemporal_store(r0, (f32x4*)dst);
        __builtin_nontemporal_store(r1, (f32x4*)(dst + 4));
    }
}

extern "C" void kernel_launch(void* const* d_in, const int* in_sizes, int n_in,
                              void* d_out, int out_size, void* d_ws, size_t ws_size,
                              hipStream_t stream) {
    const float* content = (const float*)d_in[0];
    const float* style   = (const float*)d_in[1];
    const float* w1      = (const float*)d_in[2];
    const float* b1      = (const float*)d_in[3];
    const float* w2      = (const float*)d_in[4];
    const float* b2      = (const float*)d_in[5];
    const float* wu      = (const float*)d_in[6];
    const float* bu      = (const float*)d_in[7];
    float* out = (float*)d_out;
    float* ws  = (float*)d_ws;

    float* cmean   = ws;                         // 2048
    float* crstd   = ws + 2048;                  // 2048
    float* smean   = ws + 4096;                  // 2048
    float* scov    = ws + 6144;                  // 8192 (live: softmax->final)
    __bf16* W2b    = (__bf16*)(ws + 6144);       // 4096 bf16 (dead before scov written)
    float* bias1c  = ws + 8192;                  // 1024
    float* bias1s  = ws + 9216;                  // 1024
    float* partial = ws + 14336;                 // 131072 (live: gram->softmax)
    __bf16* W1c    = (__bf16*)(ws + 14336);      // 262144 bf16 (dead before partial written)
    __bf16* W1s    = (__bf16*)(ws + 145408);     // 32768 bf16
    float* cF      = ws + 161792;                // 4194304
    float* sF      = cF + 4194304;               // 4194304

    k_stats3<<<dim3(4096), 1024, 0, stream>>>(content, style, cmean, crstd, smean);
    k_wprep<<<dim3(128, 8), 256, 0, stream>>>(w1, b1, cmean, crstd, smean,
                                              W1c, bias1c, W1s, bias1s);
    k_w2prep<<<dim3(16), 256, 0, stream>>>(w2, W2b);
    k_net_mfma<<<dim3(256, 8), 256, 0, stream>>>(content, W1c, bias1c, W2b, b2, cF, 1);
    k_net_mfma<<<dim3(256, 8), 256, 0, stream>>>(style, W1s, bias1s, W2b, b2, sF, 0);
    k_gram<<<dim3(16, 8), 256, 0, stream>>>(sF, partial);
    k_softmax<<<dim3(8), dim3(32, 32), 0, stream>>>(partial, scov);
    k_final<<<dim3(256, 8), 256, 0, stream>>>(cF, scov, wu, bu, smean, content, out);
}